// Round 14
// baseline (164.997 us; speedup 1.0000x reference)
//
#include <hip/hip_runtime.h>
#include <hip/hip_bf16.h>

#define B_ROWS  2048
#define T_DIM   8
#define IN_DIM  1024
#define OUT_DIM 4096
#define NE      12

#define M_TILE 128
#define N_TILE 128
#define K_STEP 32
#define NSTEP  (IN_DIM / K_STEP)
#define PACK_TILES 2
#define NCB    (OUT_DIM / N_TILE)   // 32 (legacy tiling)
#define NCB4   (OUT_DIM / 64)       // 64 col-blocks for the 4-wave kernel

typedef __attribute__((ext_vector_type(8))) short short8;
typedef __attribute__((ext_vector_type(4))) float f32x4;

union S8U { short8 s; unsigned u[4]; };

__device__ __forceinline__ unsigned cvt2(float a, float b) {
  __hip_bfloat162 h = __float22bfloat162_rn(make_float2(a, b));
  union { __hip_bfloat162 h; unsigned u; } c; c.h = h;
  return c.u;
}

__device__ __forceinline__ void barrier_lgkm() {
  asm volatile("s_waitcnt lgkmcnt(0)" ::: "memory");
  __builtin_amdgcn_s_barrier();
}

__device__ __forceinline__ void gload_lds16(const void* g, void* l) {
  __builtin_amdgcn_global_load_lds(
      (const __attribute__((address_space(1))) void*)g,
      (__attribute__((address_space(3))) void*)l, 16, 0, 0);
}

// ---------------- kernel P: transpose Wg[4096][12] -> WgT[12][4096] --------
__global__ __launch_bounds__(256) void wg_transpose(
    const float* __restrict__ Wg, float* __restrict__ wgt)
{
  const int c = blockIdx.x * 256 + threadIdx.x;
  #pragma unroll
  for (int e = 0; e < NE; ++e)
    wgt[(size_t)e * OUT_DIM + c] = Wg[(size_t)c * NE + e];
}

// ---------------- kernel A: gate (proven version, unchanged) ---------------
__global__ __launch_bounds__(256) void gate_kernel(
    const float* __restrict__ t, const float* __restrict__ wgt,
    const float* __restrict__ bg, int* __restrict__ counts,
    int* __restrict__ rowlist)
{
  const int b   = blockIdx.x;
  const int tid = threadIdx.x;
  const float* tb = t + (size_t)b * T_DIM * OUT_DIM;

  float4 m[4];
  #pragma unroll
  for (int it = 0; it < 4; ++it) {
    const int c = (tid + it * 256) * 4;
    float4 s = make_float4(0.f, 0.f, 0.f, 0.f);
    #pragma unroll
    for (int tt = 0; tt < T_DIM; ++tt) {
      const float4 v = *(const float4*)(tb + (size_t)tt * OUT_DIM + c);
      s.x += v.x; s.y += v.y; s.z += v.z; s.w += v.w;
    }
    m[it] = make_float4(s.x * 0.125f, s.y * 0.125f, s.z * 0.125f, s.w * 0.125f);
  }

  float part[NE];
  #pragma unroll
  for (int e = 0; e < NE; ++e) {
    float acc = 0.f;
    #pragma unroll
    for (int it = 0; it < 4; ++it) {
      const int c = (tid + it * 256) * 4;
      const float4 w = *(const float4*)(wgt + (size_t)e * OUT_DIM + c);
      acc += m[it].x * w.x; acc += m[it].y * w.y;
      acc += m[it].z * w.z; acc += m[it].w * w.w;
    }
    part[e] = acc;
  }

  double d[NE];
  #pragma unroll
  for (int e = 0; e < NE; ++e) d[e] = (double)part[e];
  #pragma unroll
  for (int off = 32; off > 0; off >>= 1) {
    #pragma unroll
    for (int e = 0; e < NE; ++e) d[e] += __shfl_down(d[e], off, 64);
  }

  __shared__ double wsred[4][NE];
  const int lane = tid & 63, wave = tid >> 6;
  if (lane == 0) {
    #pragma unroll
    for (int e = 0; e < NE; ++e) wsred[wave][e] = d[e];
  }
  __syncthreads();

  if (tid == 0) {
    double best = -1e300; int bi = 0;
    #pragma unroll
    for (int e = 0; e < NE; ++e) {
      const double v = wsred[0][e] + wsred[1][e] + wsred[2][e] + wsred[3][e] + (double)bg[e];
      if (v > best) { best = v; bi = e; }
    }
    const int pos = atomicAdd(&counts[bi], 1);
    rowlist[bi * B_ROWS + pos] = b;
  }
}

__global__ __launch_bounds__(256) void gate_fallback(
    const float* __restrict__ t, const float* __restrict__ Wg,
    const float* __restrict__ bg, int* __restrict__ counts,
    int* __restrict__ rowlist)
{
  const int b   = blockIdx.x;
  const int tid = threadIdx.x;
  const float* tb = t + (size_t)b * T_DIM * OUT_DIM;

  float part[NE];
  #pragma unroll
  for (int e = 0; e < NE; ++e) part[e] = 0.f;
  #pragma unroll
  for (int it = 0; it < 4; ++it) {
    const int c = (tid + it * 256) * 4;
    float4 s = make_float4(0.f, 0.f, 0.f, 0.f);
    #pragma unroll
    for (int tt = 0; tt < T_DIM; ++tt) {
      const float4 v = *(const float4*)(tb + (size_t)tt * OUT_DIM + c);
      s.x += v.x; s.y += v.y; s.z += v.z; s.w += v.w;
    }
    const float mm[4] = { s.x * 0.125f, s.y * 0.125f, s.z * 0.125f, s.w * 0.125f };
    #pragma unroll
    for (int j = 0; j < 4; ++j) {
      const float* wg = Wg + (size_t)(c + j) * NE;
      #pragma unroll
      for (int e = 0; e < NE; ++e) part[e] += mm[j] * wg[e];
    }
  }
  double d[NE];
  #pragma unroll
  for (int e = 0; e < NE; ++e) d[e] = (double)part[e];
  #pragma unroll
  for (int off = 32; off > 0; off >>= 1) {
    #pragma unroll
    for (int e = 0; e < NE; ++e) d[e] += __shfl_down(d[e], off, 64);
  }
  __shared__ double wsred[4][NE];
  const int lane = tid & 63, wave = tid >> 6;
  if (lane == 0) {
    #pragma unroll
    for (int e = 0; e < NE; ++e) wsred[wave][e] = d[e];
  }
  __syncthreads();
  if (tid == 0) {
    double best = -1e300; int bi = 0;
    #pragma unroll
    for (int e = 0; e < NE; ++e) {
      const double v = wsred[0][e] + wsred[1][e] + wsred[2][e] + wsred[3][e] + (double)bg[e];
      if (v > best) { best = v; bi = e; }
    }
    const int pos = atomicAdd(&counts[bi], 1);
    rowlist[bi * B_ROWS + pos] = b;
  }
}

// ---------------- kernel X: pack gathered x into bf16 fragment-slot order --
__global__ __launch_bounds__(256) void pack_x(
    const float* __restrict__ x, const int* __restrict__ counts,
    const int* __restrict__ rowlist, short8* __restrict__ pxa)
{
  const int e   = blockIdx.x;
  const int rt  = blockIdx.y;
  const int it  = blockIdx.z;
  const int cnt = counts[e];
  const int row0 = rt * M_TILE;
  if (row0 >= cnt) return;
  const int* rl = rowlist + e * B_ROWS;
  const int tid = threadIdx.x;
  const int sg = (tid >> 4) & 3, slr = tid & 15, smb = tid >> 6;

  int g0 = row0 + smb * 16 + slr;        g0 = g0 < cnt ? g0 : cnt - 1;
  int g1 = row0 + (smb + 4) * 16 + slr;  g1 = g1 < cnt ? g1 : cnt - 1;
  const float* xp0 = x + (size_t)rl[g0] * IN_DIM + sg * 8 + it * K_STEP;
  const float* xp1 = x + (size_t)rl[g1] * IN_DIM + sg * 8 + it * K_STEP;

  const float4 a = *(const float4*)xp0, b = *(const float4*)(xp0 + 4);
  const float4 c = *(const float4*)xp1, d = *(const float4*)(xp1 + 4);
  S8U v0, v1;
  v0.u[0] = cvt2(a.x, a.y); v0.u[1] = cvt2(a.z, a.w);
  v0.u[2] = cvt2(b.x, b.y); v0.u[3] = cvt2(b.z, b.w);
  v1.u[0] = cvt2(c.x, c.y); v1.u[1] = cvt2(c.z, c.w);
  v1.u[2] = cvt2(d.x, d.y); v1.u[3] = cvt2(d.z, d.w);

  short8* dst = pxa + ((size_t)(e * PACK_TILES + rt) * NSTEP + it) * 512;
  dst[tid]       = v0.s;
  dst[tid + 256] = v1.s;
}

// ---------------- kernel B4: 4-wave 256x64 GEMM, W once, 2-deep W pipeline --
// 768 blocks = exactly 3/CU (one generation, perfect balance), 16 waves/CU.
// Per step per wave: 4 A-DMA (pxa, L2) + 8 W scalar loads + 4 cvt + ds_write
// + 8 ds_read + 16 MFMA. Issue order per step: [barrier] -> A(it+1) ->
// W(it+2), so vmcnt(8) drains only A(it); W has 2 full steps of flight.
__global__ __launch_bounds__(256) void expert_gemm4(
    const float* __restrict__ W, const float* __restrict__ bias,
    const int* __restrict__ counts, const int* __restrict__ rowlist,
    const short8* __restrict__ pxa, float* __restrict__ out)
{
  const int bid = blockIdx.x;                   // [0,768)
  const int wk  = (bid & 7) * 96 + (bid >> 3);  // bijective; XCD k: [96k,96k+96)
  const int e   = wk >> 6;                      // 64 col-blocks per expert
  const int cb  = wk & 63;
  const int cnt = counts[e];
  const int c0  = cb * 64;
  const int* rl = rowlist + e * B_ROWS;

  __shared__ short8 xa[2][1024];   // 32 KiB: 256 rows x 32 k
  __shared__ short8 wb[2][256];    //  8 KiB:  64 cols x 32 k

  const int tid  = threadIdx.x;
  const int lane = tid & 63;
  const int wave = tid >> 6;       // 0..3

  // W staging: thread -> slot tid: nb=tid>>6, g=(tid>>4)&3, lc=tid&15
  const int g = (tid >> 4) & 3, lc = tid & 15, nb = tid >> 6;
  const float* wp = W + (size_t)e * IN_DIM * OUT_DIM
                      + (size_t)(g * 8) * OUT_DIM + c0 + nb * 16 + lc;

  // A source: wave w -> pxa slice rt=w>>1, local slots (w&1)*256 + [0,256)
  const short8* at = pxa + (size_t)(e * PACK_TILES + (wave >> 1)) * NSTEP * 512
                   + (wave & 1) * 256 + lane;

  f32x4 acc[4][4];   // rows wave*64 + m*16, cols c0 + n*16
  #pragma unroll
  for (int m = 0; m < 4; ++m)
    #pragma unroll
    for (int n = 0; n < 4; ++n)
      #pragma unroll
      for (int q = 0; q < 4; ++q) acc[m][n][q] = 0.f;

  float wA[8], wB[8];   // two static W register sets (2-deep)

#define W_ISSUE(SET, K)                                                 \
  {                                                                     \
    const float* p = wp + (size_t)(K) * OUT_DIM;                        \
    _Pragma("unroll")                                                   \
    for (int j = 0; j < 8; ++j) w##SET[j] = p[(size_t)j * OUT_DIM];     \
  }
#define A_DMA(IT, BUF)                                                  \
  {                                                                     \
    gload_lds16(at + (size_t)(IT) * 512,       &xa[BUF][wave * 256]);       \
    gload_lds16(at + (size_t)(IT) * 512 + 64,  &xa[BUF][wave * 256 + 64]);  \
    gload_lds16(at + (size_t)(IT) * 512 + 128, &xa[BUF][wave * 256 + 128]); \
    gload_lds16(at + (size_t)(IT) * 512 + 192, &xa[BUF][wave * 256 + 192]); \
    __builtin_amdgcn_sched_barrier(0);                                  \
  }
#define GEMM_STEP(SET, IT)                                              \
  {                                                                     \
    const int buf = (IT) & 1;                                           \
    S8U bv;                                                             \
    _Pragma("unroll")                                                   \
    for (int q = 0; q < 4; ++q)                                         \
      bv.u[q] = cvt2(w##SET[2 * q], w##SET[2 * q + 1]);                 \
    wb[buf][tid] = bv.s;                                                \
    asm volatile("s_waitcnt vmcnt(8) lgkmcnt(0)" ::: "memory");         \
    __builtin_amdgcn_s_barrier();                                       \
    A_DMA(((IT) + 1) & (NSTEP - 1), buf ^ 1);                           \
    W_ISSUE(SET, (((IT) + 2) & (NSTEP - 1)) * K_STEP);                  \
    __builtin_amdgcn_sched_barrier(0);                                  \
    short8 af[4], bf[4];                                                \
    _Pragma("unroll")                                                   \
    for (int m = 0; m < 4; ++m)                                         \
      af[m] = xa[buf][wave * 256 + m * 64 + lane];                      \
    _Pragma("unroll")                                                   \
    for (int n = 0; n < 4; ++n)                                         \
      bf[n] = wb[buf][n * 64 + lane];                                   \
    _Pragma("unroll")                                                   \
    for (int m = 0; m < 4; ++m)                                         \
      _Pragma("unroll")                                                 \
      for (int n = 0; n < 4; ++n)                                       \
        acc[m][n] = __builtin_amdgcn_mfma_f32_16x16x32_bf16(            \
            af[m], bf[n], acc[m][n], 0, 0, 0);                          \
  }

  // prologue: A(0) oldest, then W(0), W(1)
  A_DMA(0, 0);
  W_ISSUE(A, 0);
  W_ISSUE(B, K_STEP);
  __builtin_amdgcn_sched_barrier(0);

  for (int it = 0; it < NSTEP; it += 2) {
    GEMM_STEP(A, it);
    GEMM_STEP(B, it + 1);
  }
#undef GEMM_STEP
#undef A_DMA
#undef W_ISSUE

  // epilogue: C/D layout col = lane&15, row = (lane>>4)*4 + r
  const int lr = lane & 15;
  const int lq = (lane >> 4) * 4;
  float bcol[4];
  #pragma unroll
  for (int n = 0; n < 4; ++n)
    bcol[n] = bias[e * OUT_DIM + c0 + n * 16 + lr];

  #pragma unroll
  for (int m = 0; m < 4; ++m) {
    #pragma unroll
    for (int r = 0; r < 4; ++r) {
      const int gidx = wave * 64 + m * 16 + lq + r;
      if (gidx >= cnt) continue;
      const int grow = rl[gidx];
      float* orow = out + (size_t)grow * OUT_DIM;
      #pragma unroll
      for (int n = 0; n < 4; ++n) {
        const int col = c0 + n * 16 + lr;
        orow[col] = acc[m][n][r] + bcol[n];
      }
    }
  }
}

// ---------------- kernel B2: legacy r5 GEMM (fallback + cnt>256 catcher) ----
__global__ __launch_bounds__(256) void expert_gemm_legacy(
    const float* __restrict__ x, const float* __restrict__ W,
    const float* __restrict__ bias, const int* __restrict__ counts,
    const int* __restrict__ rowlist, float* __restrict__ out, int y_off)
{
  const int e    = blockIdx.z;
  const int cnt  = counts[e];
  const int row0 = (blockIdx.y + y_off) * M_TILE;
  if (row0 >= cnt) return;
  const int c0   = blockIdx.x * N_TILE;
  const int* rl  = rowlist + e * B_ROWS;

  __shared__ short8 xa[2][512];
  __shared__ short8 wb[2][512];

  const int tid  = threadIdx.x;
  const int lane = tid & 63;
  const int wave = tid >> 6;
  const int sg  = (tid >> 4) & 3;
  const int slr = tid & 15;
  const int smb = tid >> 6;

  int arow0, arow1;
  {
    const int g0 = row0 + smb * 16 + slr;
    const int g1 = row0 + (smb + 4) * 16 + slr;
    arow0 = rl[g0 < cnt ? g0 : cnt - 1];
    arow1 = rl[g1 < cnt ? g1 : cnt - 1];
  }
  const float* xp0 = x + (size_t)arow0 * IN_DIM + sg * 8;
  const float* xp1 = x + (size_t)arow1 * IN_DIM + sg * 8;
  const float* wp  = W + (size_t)e * IN_DIM * OUT_DIM
                       + (size_t)(sg * 8) * OUT_DIM + c0 + smb * 16 + slr;

  const int wm = (wave >> 1) * 64;
  const int wn = (wave & 1) * 64;
  const int abase = (wave >> 1) * 256;
  const int bbase = (wave & 1) * 256;

  f32x4 acc[4][4];
  #pragma unroll
  for (int m = 0; m < 4; ++m)
    #pragma unroll
    for (int n = 0; n < 4; ++n)
      #pragma unroll
      for (int q = 0; q < 4; ++q) acc[m][n][q] = 0.f;

  float4 a0lo, a0hi, a1lo, a1hi;
  float w0[8], w1[8];

#define ISSUE_LOADS(K)                                                  \
  {                                                                     \
    a0lo = *(const float4*)(xp0 + (K));                                 \
    a0hi = *(const float4*)(xp0 + (K) + 4);                             \
    a1lo = *(const float4*)(xp1 + (K));                                 \
    a1hi = *(const float4*)(xp1 + (K) + 4);                             \
    const float* p = wp + (size_t)(K) * OUT_DIM;                        \
    _Pragma("unroll")                                                   \
    for (int j = 0; j < 8; ++j) {                                       \
      w0[j] = p[(size_t)j * OUT_DIM];                                   \
      w1[j] = p[(size_t)j * OUT_DIM + 64];                              \
    }                                                                   \
  }

  ISSUE_LOADS(0);

  for (int it = 0; it < NSTEP; ++it) {
    S8U av0, av1, bv0, bv1;
    av0.u[0] = cvt2(a0lo.x, a0lo.y); av0.u[1] = cvt2(a0lo.z, a0lo.w);
    av0.u[2] = cvt2(a0hi.x, a0hi.y); av0.u[3] = cvt2(a0hi.z, a0hi.w);
    av1.u[0] = cvt2(a1lo.x, a1lo.y); av1.u[1] = cvt2(a1lo.z, a1lo.w);
    av1.u[2] = cvt2(a1hi.x, a1hi.y); av1.u[3] = cvt2(a1hi.z, a1hi.w);
    #pragma unroll
    for (int q = 0; q < 4; ++q) {
      bv0.u[q] = cvt2(w0[2 * q], w0[2 * q + 1]);
      bv1.u[q] = cvt2(w1[2 * q], w1[2 * q + 1]);
    }

    if (it + 1 < NSTEP) ISSUE_LOADS((it + 1) * K_STEP);

    const int buf = it & 1;
    xa[buf][tid]       = av0.s;
    xa[buf][tid + 256] = av1.s;
    wb[buf][tid]       = bv0.s;
    wb[buf][tid + 256] = bv1.s;
    barrier_lgkm();

    short8 af[4], bf[4];
    #pragma unroll
    for (int m = 0; m < 4; ++m) af[m] = xa[buf][abase + m * 64 + lane];
    #pragma unroll
    for (int n = 0; n < 4; ++n) bf[n] = wb[buf][bbase + n * 64 + lane];
    #pragma unroll
    for (int m = 0; m < 4; ++m)
      #pragma unroll
      for (int n = 0; n < 4; ++n)
        acc[m][n] = __builtin_amdgcn_mfma_f32_16x16x32_bf16(af[m], bf[n], acc[m][n], 0, 0, 0);
  }
#undef ISSUE_LOADS

  const int lr = lane & 15;
  const int lq = (lane >> 4) * 4;
  float bcol[4];
  #pragma unroll
  for (int n = 0; n < 4; ++n)
    bcol[n] = bias[e * OUT_DIM + c0 + wn + n * 16 + lr];

  #pragma unroll
  for (int m = 0; m < 4; ++m) {
    #pragma unroll
    for (int r = 0; r < 4; ++r) {
      const int gidx = row0 + wm + m * 16 + lq + r;
      if (gidx >= cnt) continue;
      const int grow = rl[gidx];
      float* orow = out + (size_t)grow * OUT_DIM;
      #pragma unroll
      for (int n = 0; n < 4; ++n) {
        const int col = c0 + wn + n * 16 + lr;
        orow[col] = acc[m][n][r] + bcol[n];
      }
    }
  }
}

extern "C" void kernel_launch(void* const* d_in, const int* in_sizes, int n_in,
                              void* d_out, int out_size, void* d_ws, size_t ws_size,
                              hipStream_t stream) {
  (void)in_sizes; (void)n_in; (void)out_size;
  const float* x  = (const float*)d_in[0];
  const float* t  = (const float*)d_in[1];
  const float* W  = (const float*)d_in[2];
  const float* bb = (const float*)d_in[3];
  const float* Wg = (const float*)d_in[4];
  const float* bg = (const float*)d_in[5];
  float* out = (float*)d_out;

  char*  base    = (char*)d_ws;
  int*   counts  = (int*)base;                       // 64 B
  int*   rowlist = (int*)(base + 64);                // 98304 B
  float* wgt     = (float*)(base + 98368);           // 196608 B -> ends 294976
  short8* pxa    = (short8*)(base + 295936);         // 6 MB
  const size_t need_wgt  = 294976;
  const size_t need_pack = 295936 + (size_t)NE * PACK_TILES * NSTEP * 512 * 16;

  hipMemsetAsync(counts, 0, 64, stream);
  if (ws_size >= need_wgt) {
    wg_transpose<<<OUT_DIM / 256, 256, 0, stream>>>(Wg, wgt);
    gate_kernel<<<B_ROWS, 256, 0, stream>>>(t, wgt, bg, counts, rowlist);
  } else {
    gate_fallback<<<B_ROWS, 256, 0, stream>>>(t, Wg, bg, counts, rowlist);
  }

  if (ws_size >= need_pack) {
    pack_x<<<dim3(NE, PACK_TILES, NSTEP), 256, 0, stream>>>(x, counts, rowlist, pxa);
    expert_gemm4<<<dim3(NE * NCB4, 1, 1), 256, 0, stream>>>(
        W, bb, counts, rowlist, pxa, out);
    // catcher for the (statistically impossible) cnt > 256 tail
    expert_gemm_legacy<<<dim3(NCB, B_ROWS / M_TILE - PACK_TILES, NE),
                         256, 0, stream>>>(x, W, bb, counts, rowlist, out, PACK_TILES);
  } else {
    expert_gemm_legacy<<<dim3(NCB, B_ROWS / M_TILE, NE),
                         256, 0, stream>>>(x, W, bb, counts, rowlist, out, 0);
  }
}

// Round 15
// 151.695 us; speedup vs baseline: 1.0877x; 1.0877x over previous
//
#include <hip/hip_runtime.h>
#include <hip/hip_bf16.h>

#define B_ROWS  2048
#define T_DIM   8
#define IN_DIM  1024
#define OUT_DIM 4096
#define NE      12

#define M_TILE 128
#define N_TILE 128
#define K_STEP 32
#define NSTEP  (IN_DIM / K_STEP)
#define PACK_TILES 2
#define NCB    (OUT_DIM / N_TILE)   // 32 (legacy tiling)
#define NCB16  (OUT_DIM / 256)      // 16 col-blocks for the N=256 kernel

typedef __attribute__((ext_vector_type(8))) short short8;
typedef __attribute__((ext_vector_type(4))) float f32x4;

union S8U { short8 s; unsigned u[4]; };

__device__ __forceinline__ unsigned cvt2(float a, float b) {
  __hip_bfloat162 h = __float22bfloat162_rn(make_float2(a, b));
  union { __hip_bfloat162 h; unsigned u; } c; c.h = h;
  return c.u;
}

__device__ __forceinline__ void barrier_lgkm() {
  asm volatile("s_waitcnt lgkmcnt(0)" ::: "memory");
  __builtin_amdgcn_s_barrier();
}

__device__ __forceinline__ void gload_lds16(const void* g, void* l) {
  __builtin_amdgcn_global_load_lds(
      (const __attribute__((address_space(1))) void*)g,
      (__attribute__((address_space(3))) void*)l, 16, 0, 0);
}

// ---------------- kernel P: transpose Wg[4096][12] -> WgT[12][4096] --------
__global__ __launch_bounds__(256) void wg_transpose(
    const float* __restrict__ Wg, float* __restrict__ wgt)
{
  const int c = blockIdx.x * 256 + threadIdx.x;
  #pragma unroll
  for (int e = 0; e < NE; ++e)
    wgt[(size_t)e * OUT_DIM + c] = Wg[(size_t)c * NE + e];
}

// ---------------- kernel A: gate (proven version, unchanged) ---------------
__global__ __launch_bounds__(256) void gate_kernel(
    const float* __restrict__ t, const float* __restrict__ wgt,
    const float* __restrict__ bg, int* __restrict__ counts,
    int* __restrict__ rowlist)
{
  const int b   = blockIdx.x;
  const int tid = threadIdx.x;
  const float* tb = t + (size_t)b * T_DIM * OUT_DIM;

  float4 m[4];
  #pragma unroll
  for (int it = 0; it < 4; ++it) {
    const int c = (tid + it * 256) * 4;
    float4 s = make_float4(0.f, 0.f, 0.f, 0.f);
    #pragma unroll
    for (int tt = 0; tt < T_DIM; ++tt) {
      const float4 v = *(const float4*)(tb + (size_t)tt * OUT_DIM + c);
      s.x += v.x; s.y += v.y; s.z += v.z; s.w += v.w;
    }
    m[it] = make_float4(s.x * 0.125f, s.y * 0.125f, s.z * 0.125f, s.w * 0.125f);
  }

  float part[NE];
  #pragma unroll
  for (int e = 0; e < NE; ++e) {
    float acc = 0.f;
    #pragma unroll
    for (int it = 0; it < 4; ++it) {
      const int c = (tid + it * 256) * 4;
      const float4 w = *(const float4*)(wgt + (size_t)e * OUT_DIM + c);
      acc += m[it].x * w.x; acc += m[it].y * w.y;
      acc += m[it].z * w.z; acc += m[it].w * w.w;
    }
    part[e] = acc;
  }

  double d[NE];
  #pragma unroll
  for (int e = 0; e < NE; ++e) d[e] = (double)part[e];
  #pragma unroll
  for (int off = 32; off > 0; off >>= 1) {
    #pragma unroll
    for (int e = 0; e < NE; ++e) d[e] += __shfl_down(d[e], off, 64);
  }

  __shared__ double wsred[4][NE];
  const int lane = tid & 63, wave = tid >> 6;
  if (lane == 0) {
    #pragma unroll
    for (int e = 0; e < NE; ++e) wsred[wave][e] = d[e];
  }
  __syncthreads();

  if (tid == 0) {
    double best = -1e300; int bi = 0;
    #pragma unroll
    for (int e = 0; e < NE; ++e) {
      const double v = wsred[0][e] + wsred[1][e] + wsred[2][e] + wsred[3][e] + (double)bg[e];
      if (v > best) { best = v; bi = e; }
    }
    const int pos = atomicAdd(&counts[bi], 1);
    rowlist[bi * B_ROWS + pos] = b;
  }
}

__global__ __launch_bounds__(256) void gate_fallback(
    const float* __restrict__ t, const float* __restrict__ Wg,
    const float* __restrict__ bg, int* __restrict__ counts,
    int* __restrict__ rowlist)
{
  const int b   = blockIdx.x;
  const int tid = threadIdx.x;
  const float* tb = t + (size_t)b * T_DIM * OUT_DIM;

  float part[NE];
  #pragma unroll
  for (int e = 0; e < NE; ++e) part[e] = 0.f;
  #pragma unroll
  for (int it = 0; it < 4; ++it) {
    const int c = (tid + it * 256) * 4;
    float4 s = make_float4(0.f, 0.f, 0.f, 0.f);
    #pragma unroll
    for (int tt = 0; tt < T_DIM; ++tt) {
      const float4 v = *(const float4*)(tb + (size_t)tt * OUT_DIM + c);
      s.x += v.x; s.y += v.y; s.z += v.z; s.w += v.w;
    }
    const float mm[4] = { s.x * 0.125f, s.y * 0.125f, s.z * 0.125f, s.w * 0.125f };
    #pragma unroll
    for (int j = 0; j < 4; ++j) {
      const float* wg = Wg + (size_t)(c + j) * NE;
      #pragma unroll
      for (int e = 0; e < NE; ++e) part[e] += mm[j] * wg[e];
    }
  }
  double d[NE];
  #pragma unroll
  for (int e = 0; e < NE; ++e) d[e] = (double)part[e];
  #pragma unroll
  for (int off = 32; off > 0; off >>= 1) {
    #pragma unroll
    for (int e = 0; e < NE; ++e) d[e] += __shfl_down(d[e], off, 64);
  }
  __shared__ double wsred[4][NE];
  const int lane = tid & 63, wave = tid >> 6;
  if (lane == 0) {
    #pragma unroll
    for (int e = 0; e < NE; ++e) wsred[wave][e] = d[e];
  }
  __syncthreads();
  if (tid == 0) {
    double best = -1e300; int bi = 0;
    #pragma unroll
    for (int e = 0; e < NE; ++e) {
      const double v = wsred[0][e] + wsred[1][e] + wsred[2][e] + wsred[3][e] + (double)bg[e];
      if (v > best) { best = v; bi = e; }
    }
    const int pos = atomicAdd(&counts[bi], 1);
    rowlist[bi * B_ROWS + pos] = b;
  }
}

// ---------------- kernel X: pack gathered x into bf16 fragment-slot order --
__global__ __launch_bounds__(256) void pack_x(
    const float* __restrict__ x, const int* __restrict__ counts,
    const int* __restrict__ rowlist, short8* __restrict__ pxa)
{
  const int e   = blockIdx.x;
  const int rt  = blockIdx.y;
  const int it  = blockIdx.z;
  const int cnt = counts[e];
  const int row0 = rt * M_TILE;
  if (row0 >= cnt) return;
  const int* rl = rowlist + e * B_ROWS;
  const int tid = threadIdx.x;
  const int sg = (tid >> 4) & 3, slr = tid & 15, smb = tid >> 6;

  int g0 = row0 + smb * 16 + slr;        g0 = g0 < cnt ? g0 : cnt - 1;
  int g1 = row0 + (smb + 4) * 16 + slr;  g1 = g1 < cnt ? g1 : cnt - 1;
  const float* xp0 = x + (size_t)rl[g0] * IN_DIM + sg * 8 + it * K_STEP;
  const float* xp1 = x + (size_t)rl[g1] * IN_DIM + sg * 8 + it * K_STEP;

  const float4 a = *(const float4*)xp0, b = *(const float4*)(xp0 + 4);
  const float4 c = *(const float4*)xp1, d = *(const float4*)(xp1 + 4);
  S8U v0, v1;
  v0.u[0] = cvt2(a.x, a.y); v0.u[1] = cvt2(a.z, a.w);
  v0.u[2] = cvt2(b.x, b.y); v0.u[3] = cvt2(b.z, b.w);
  v1.u[0] = cvt2(c.x, c.y); v1.u[1] = cvt2(c.z, c.w);
  v1.u[2] = cvt2(d.x, d.y); v1.u[3] = cvt2(d.z, d.w);

  short8* dst = pxa + ((size_t)(e * PACK_TILES + rt) * NSTEP + it) * 512;
  dst[tid]       = v0.s;
  dst[tid + 256] = v1.s;
}

// ---------------- kernel B16: 8-wave 256x256 GEMM, min delivered bytes ------
// 192 blocks (12e x 16cb) -> at most 1 block/CU: max per-CU bytes 1.75 MB
// (vs r13's 2.3 on the doubled-up CUs). Total gemm bytes: W 192 (once) +
// pxa 96 (16 re-reads, XCD-clustered) + out 32 = 320 MB. Schedule = r13's
// counted-vmcnt shape: A(it) 2 DMA drained by vmcnt(16) while W(it+1)'s 16
// scalar loads stay in flight across the barrier.
__global__ __launch_bounds__(512) void expert_gemm16(
    const float* __restrict__ W, const float* __restrict__ bias,
    const int* __restrict__ counts, const int* __restrict__ rowlist,
    const short8* __restrict__ pxa, float* __restrict__ out)
{
  const int bid = blockIdx.x;                   // [0,192)
  const int wk  = (bid & 7) * 24 + (bid >> 3);  // bijective; XCD k: [24k,24k+24)
  const int e   = wk >> 4;                      // 16 col-blocks per expert
  const int cb  = wk & 15;
  const int cnt = counts[e];
  const int c0  = cb * 256;
  const int* rl = rowlist + e * B_ROWS;

  __shared__ short8 xa[2][1024];   // 32 KiB: 256 rows x 32 k
  __shared__ short8 wb[2][1024];   // 32 KiB: 256 cols x 32 k

  const int tid  = threadIdx.x;    // 0..511
  const int lane = tid & 63;
  const int wave = tid >> 6;       // 0..7

  // W staging: thread -> slots {tid, tid+512}.
  // slot s: col = (s>>6)*16 + (s&15), k = ((s>>4)&3)*8 + j
  const int g = (tid >> 4) & 3, lc = tid & 15, nb = tid >> 6;
  const float* wp = W + (size_t)e * IN_DIM * OUT_DIM
                      + (size_t)(g * 8) * OUT_DIM + c0 + nb * 16 + lc;
  // slot tid+512: nb+8 -> col +128

  // A staging: wave w stages xa slots [w*128,(w+1)*128) = rows [32w,32w+32)
  // from pxa slice rt=w>>2, local slots (w&3)*128 + [0,128)
  const short8* at = pxa + (size_t)(e * PACK_TILES + (wave >> 2)) * NSTEP * 512
                   + (wave & 3) * 128 + lane;

  // MFMA geometry: wave w -> rows [(w>>1)*64, +64) x cols [(w&1)*128, +128)
  const int wm = (wave >> 1) * 64;
  const int wn = (wave & 1) * 128;
  const int abase = wm * 4;        // = (wm/16)*64
  const int bbase = wn * 4;

  f32x4 acc[4][8];
  #pragma unroll
  for (int m = 0; m < 4; ++m)
    #pragma unroll
    for (int n = 0; n < 8; ++n)
      #pragma unroll
      for (int q = 0; q < 4; ++q) acc[m][n][q] = 0.f;

  float w0[8], w1[8];

#define W_ISSUE(K)                                                      \
  {                                                                     \
    const float* p = wp + (size_t)(K) * OUT_DIM;                        \
    _Pragma("unroll")                                                   \
    for (int j = 0; j < 8; ++j) {                                       \
      w0[j] = p[(size_t)j * OUT_DIM];                                   \
      w1[j] = p[(size_t)j * OUT_DIM + 128];                             \
    }                                                                   \
  }
#define A_DMA(IT, BUF)                                                  \
  {                                                                     \
    gload_lds16(at + (size_t)(IT) * 512,      &xa[BUF][wave * 128]);    \
    gload_lds16(at + (size_t)(IT) * 512 + 64, &xa[BUF][wave * 128 + 64]); \
    __builtin_amdgcn_sched_barrier(0);                                  \
  }

  W_ISSUE(0);
  A_DMA(0, 0);

  for (int it = 0; it < NSTEP; ++it) {
    const int buf = it & 1;
    const int itn = (it + 1) & (NSTEP - 1);   // wrap keeps vmcnt uniform

    // convert W(it): dep-wait drains its 16 loads; A(it) DMAs stay in flight
    S8U bv0, bv1;
    #pragma unroll
    for (int q = 0; q < 4; ++q) {
      bv0.u[q] = cvt2(w0[2 * q], w0[2 * q + 1]);
      bv1.u[q] = cvt2(w1[2 * q], w1[2 * q + 1]);
    }

    W_ISSUE(itn * K_STEP);        // 16 loads in flight across the barrier
    wb[buf][tid]       = bv0.s;
    wb[buf][tid + 512] = bv1.s;

    // drain A(it) (2 oldest) + ds_write; keep W(it+1) (16 youngest) flying
    asm volatile("s_waitcnt vmcnt(16) lgkmcnt(0)" ::: "memory");
    __builtin_amdgcn_s_barrier();

    A_DMA(itn, buf ^ 1);          // safe: all reads of buf^1 completed

    short8 af[4], bf[8];
    #pragma unroll
    for (int m = 0; m < 4; ++m) af[m] = xa[buf][abase + m * 64 + lane];
    #pragma unroll
    for (int n = 0; n < 8; ++n) bf[n] = wb[buf][bbase + n * 64 + lane];
    #pragma unroll
    for (int m = 0; m < 4; ++m)
      #pragma unroll
      for (int n = 0; n < 8; ++n)
        acc[m][n] = __builtin_amdgcn_mfma_f32_16x16x32_bf16(af[m], bf[n], acc[m][n], 0, 0, 0);
  }
#undef W_ISSUE
#undef A_DMA

  // epilogue: C/D layout col = lane&15, row = (lane>>4)*4 + r
  const int lr = lane & 15;
  const int lq = (lane >> 4) * 4;
  float bcol[8];
  #pragma unroll
  for (int n = 0; n < 8; ++n)
    bcol[n] = bias[e * OUT_DIM + c0 + wn + n * 16 + lr];

  #pragma unroll
  for (int m = 0; m < 4; ++m) {
    #pragma unroll
    for (int r = 0; r < 4; ++r) {
      const int gidx = wm + m * 16 + lq + r;
      if (gidx >= cnt) continue;
      const int grow = rl[gidx];
      float* orow = out + (size_t)grow * OUT_DIM;
      #pragma unroll
      for (int n = 0; n < 8; ++n) {
        const int col = c0 + wn + n * 16 + lr;
        orow[col] = acc[m][n][r] + bcol[n];
      }
    }
  }
}

// ---------------- kernel B2: legacy r5 GEMM (fallback + cnt>256 catcher) ----
__global__ __launch_bounds__(256) void expert_gemm_legacy(
    const float* __restrict__ x, const float* __restrict__ W,
    const float* __restrict__ bias, const int* __restrict__ counts,
    const int* __restrict__ rowlist, float* __restrict__ out, int y_off)
{
  const int e    = blockIdx.z;
  const int cnt  = counts[e];
  const int row0 = (blockIdx.y + y_off) * M_TILE;
  if (row0 >= cnt) return;
  const int c0   = blockIdx.x * N_TILE;
  const int* rl  = rowlist + e * B_ROWS;

  __shared__ short8 xa[2][512];
  __shared__ short8 wb[2][512];

  const int tid  = threadIdx.x;
  const int lane = tid & 63;
  const int wave = tid >> 6;
  const int sg  = (tid >> 4) & 3;
  const int slr = tid & 15;
  const int smb = tid >> 6;

  int arow0, arow1;
  {
    const int g0 = row0 + smb * 16 + slr;
    const int g1 = row0 + (smb + 4) * 16 + slr;
    arow0 = rl[g0 < cnt ? g0 : cnt - 1];
    arow1 = rl[g1 < cnt ? g1 : cnt - 1];
  }
  const float* xp0 = x + (size_t)arow0 * IN_DIM + sg * 8;
  const float* xp1 = x + (size_t)arow1 * IN_DIM + sg * 8;
  const float* wp  = W + (size_t)e * IN_DIM * OUT_DIM
                       + (size_t)(sg * 8) * OUT_DIM + c0 + smb * 16 + slr;

  const int wm = (wave >> 1) * 64;
  const int wn = (wave & 1) * 64;
  const int abase = (wave >> 1) * 256;
  const int bbase = (wave & 1) * 256;

  f32x4 acc[4][4];
  #pragma unroll
  for (int m = 0; m < 4; ++m)
    #pragma unroll
    for (int n = 0; n < 4; ++n)
      #pragma unroll
      for (int q = 0; q < 4; ++q) acc[m][n][q] = 0.f;

  float4 a0lo, a0hi, a1lo, a1hi;
  float w0[8], w1[8];

#define ISSUE_LOADS(K)                                                  \
  {                                                                     \
    a0lo = *(const float4*)(xp0 + (K));                                 \
    a0hi = *(const float4*)(xp0 + (K) + 4);                             \
    a1lo = *(const float4*)(xp1 + (K));                                 \
    a1hi = *(const float4*)(xp1 + (K) + 4);                             \
    const float* p = wp + (size_t)(K) * OUT_DIM;                        \
    _Pragma("unroll")                                                   \
    for (int j = 0; j < 8; ++j) {                                       \
      w0[j] = p[(size_t)j * OUT_DIM];                                   \
      w1[j] = p[(size_t)j * OUT_DIM + 64];                              \
    }                                                                   \
  }

  ISSUE_LOADS(0);

  for (int it = 0; it < NSTEP; ++it) {
    S8U av0, av1, bv0, bv1;
    av0.u[0] = cvt2(a0lo.x, a0lo.y); av0.u[1] = cvt2(a0lo.z, a0lo.w);
    av0.u[2] = cvt2(a0hi.x, a0hi.y); av0.u[3] = cvt2(a0hi.z, a0hi.w);
    av1.u[0] = cvt2(a1lo.x, a1lo.y); av1.u[1] = cvt2(a1lo.z, a1lo.w);
    av1.u[2] = cvt2(a1hi.x, a1hi.y); av1.u[3] = cvt2(a1hi.z, a1hi.w);
    #pragma unroll
    for (int q = 0; q < 4; ++q) {
      bv0.u[q] = cvt2(w0[2 * q], w0[2 * q + 1]);
      bv1.u[q] = cvt2(w1[2 * q], w1[2 * q + 1]);
    }

    if (it + 1 < NSTEP) ISSUE_LOADS((it + 1) * K_STEP);

    const int buf = it & 1;
    xa[buf][tid]       = av0.s;
    xa[buf][tid + 256] = av1.s;
    wb[buf][tid]       = bv0.s;
    wb[buf][tid + 256] = bv1.s;
    barrier_lgkm();

    short8 af[4], bf[4];
    #pragma unroll
    for (int m = 0; m < 4; ++m) af[m] = xa[buf][abase + m * 64 + lane];
    #pragma unroll
    for (int n = 0; n < 4; ++n) bf[n] = wb[buf][bbase + n * 64 + lane];
    #pragma unroll
    for (int m = 0; m < 4; ++m)
      #pragma unroll
      for (int n = 0; n < 4; ++n)
        acc[m][n] = __builtin_amdgcn_mfma_f32_16x16x32_bf16(af[m], bf[n], acc[m][n], 0, 0, 0);
  }
#undef ISSUE_LOADS

  const int lr = lane & 15;
  const int lq = (lane >> 4) * 4;
  float bcol[4];
  #pragma unroll
  for (int n = 0; n < 4; ++n)
    bcol[n] = bias[e * OUT_DIM + c0 + wn + n * 16 + lr];

  #pragma unroll
  for (int m = 0; m < 4; ++m) {
    #pragma unroll
    for (int r = 0; r < 4; ++r) {
      const int gidx = row0 + wm + m * 16 + lq + r;
      if (gidx >= cnt) continue;
      const int grow = rl[gidx];
      float* orow = out + (size_t)grow * OUT_DIM;
      #pragma unroll
      for (int n = 0; n < 4; ++n) {
        const int col = c0 + wn + n * 16 + lr;
        orow[col] = acc[m][n][r] + bcol[n];
      }
    }
  }
}

extern "C" void kernel_launch(void* const* d_in, const int* in_sizes, int n_in,
                              void* d_out, int out_size, void* d_ws, size_t ws_size,
                              hipStream_t stream) {
  (void)in_sizes; (void)n_in; (void)out_size;
  const float* x  = (const float*)d_in[0];
  const float* t  = (const float*)d_in[1];
  const float* W  = (const float*)d_in[2];
  const float* bb = (const float*)d_in[3];
  const float* Wg = (const float*)d_in[4];
  const float* bg = (const float*)d_in[5];
  float* out = (float*)d_out;

  char*  base    = (char*)d_ws;
  int*   counts  = (int*)base;                       // 64 B
  int*   rowlist = (int*)(base + 64);                // 98304 B
  float* wgt     = (float*)(base + 98368);           // 196608 B -> ends 294976
  short8* pxa    = (short8*)(base + 295936);         // 6 MB
  const size_t need_wgt  = 294976;
  const size_t need_pack = 295936 + (size_t)NE * PACK_TILES * NSTEP * 512 * 16;

  hipMemsetAsync(counts, 0, 64, stream);
  if (ws_size >= need_wgt) {
    wg_transpose<<<OUT_DIM / 256, 256, 0, stream>>>(Wg, wgt);
    gate_kernel<<<B_ROWS, 256, 0, stream>>>(t, wgt, bg, counts, rowlist);
  } else {
    gate_fallback<<<B_ROWS, 256, 0, stream>>>(t, Wg, bg, counts, rowlist);
  }

  if (ws_size >= need_pack) {
    pack_x<<<dim3(NE, PACK_TILES, NSTEP), 256, 0, stream>>>(x, counts, rowlist, pxa);
    expert_gemm16<<<dim3(NE * NCB16, 1, 1), 512, 0, stream>>>(
        W, bb, counts, rowlist, pxa, out);
    // catcher for the (statistically impossible) cnt > 256 tail
    expert_gemm_legacy<<<dim3(NCB, B_ROWS / M_TILE - PACK_TILES, NE),
                         256, 0, stream>>>(x, W, bb, counts, rowlist, out, PACK_TILES);
  } else {
    expert_gemm_legacy<<<dim3(NCB, B_ROWS / M_TILE, NE),
                         256, 0, stream>>>(x, W, bb, counts, rowlist, out, 0);
  }
}

// Round 16
// 145.088 us; speedup vs baseline: 1.1372x; 1.0455x over previous
//
#include <hip/hip_runtime.h>
#include <hip/hip_bf16.h>

#define B_ROWS  2048
#define T_DIM   8
#define IN_DIM  1024
#define OUT_DIM 4096
#define NE      12

#define M_TILE 128
#define N_TILE 128
#define K_STEP 32
#define NSTEP  (IN_DIM / K_STEP)
#define PACK_TILES 2
#define NCB    (OUT_DIM / N_TILE)   // 32 (legacy tiling)
#define NCB16  (OUT_DIM / 256)      // 16 col-blocks (N=256 kernel)

typedef __attribute__((ext_vector_type(8))) short short8;
typedef __attribute__((ext_vector_type(4))) float f32x4;

union S8U { short8 s; unsigned u[4]; };

__device__ __forceinline__ unsigned cvt2(float a, float b) {
  __hip_bfloat162 h = __float22bfloat162_rn(make_float2(a, b));
  union { __hip_bfloat162 h; unsigned u; } c; c.h = h;
  return c.u;
}

__device__ __forceinline__ void barrier_lgkm() {
  asm volatile("s_waitcnt lgkmcnt(0)" ::: "memory");
  __builtin_amdgcn_s_barrier();
}

__device__ __forceinline__ void gload_lds16(const void* g, void* l) {
  __builtin_amdgcn_global_load_lds(
      (const __attribute__((address_space(1))) void*)g,
      (__attribute__((address_space(3))) void*)l, 16, 0, 0);
}

// ---------------- kernel P: transpose Wg[4096][12] -> WgT[12][4096] --------
__global__ __launch_bounds__(256) void wg_transpose(
    const float* __restrict__ Wg, float* __restrict__ wgt)
{
  const int c = blockIdx.x * 256 + threadIdx.x;
  #pragma unroll
  for (int e = 0; e < NE; ++e)
    wgt[(size_t)e * OUT_DIM + c] = Wg[(size_t)c * NE + e];
}

// ---------------- kernel A: gate (proven version, unchanged) ---------------
__global__ __launch_bounds__(256) void gate_kernel(
    const float* __restrict__ t, const float* __restrict__ wgt,
    const float* __restrict__ bg, int* __restrict__ counts,
    int* __restrict__ rowlist)
{
  const int b   = blockIdx.x;
  const int tid = threadIdx.x;
  const float* tb = t + (size_t)b * T_DIM * OUT_DIM;

  float4 m[4];
  #pragma unroll
  for (int it = 0; it < 4; ++it) {
    const int c = (tid + it * 256) * 4;
    float4 s = make_float4(0.f, 0.f, 0.f, 0.f);
    #pragma unroll
    for (int tt = 0; tt < T_DIM; ++tt) {
      const float4 v = *(const float4*)(tb + (size_t)tt * OUT_DIM + c);
      s.x += v.x; s.y += v.y; s.z += v.z; s.w += v.w;
    }
    m[it] = make_float4(s.x * 0.125f, s.y * 0.125f, s.z * 0.125f, s.w * 0.125f);
  }

  float part[NE];
  #pragma unroll
  for (int e = 0; e < NE; ++e) {
    float acc = 0.f;
    #pragma unroll
    for (int it = 0; it < 4; ++it) {
      const int c = (tid + it * 256) * 4;
      const float4 w = *(const float4*)(wgt + (size_t)e * OUT_DIM + c);
      acc += m[it].x * w.x; acc += m[it].y * w.y;
      acc += m[it].z * w.z; acc += m[it].w * w.w;
    }
    part[e] = acc;
  }

  double d[NE];
  #pragma unroll
  for (int e = 0; e < NE; ++e) d[e] = (double)part[e];
  #pragma unroll
  for (int off = 32; off > 0; off >>= 1) {
    #pragma unroll
    for (int e = 0; e < NE; ++e) d[e] += __shfl_down(d[e], off, 64);
  }

  __shared__ double wsred[4][NE];
  const int lane = tid & 63, wave = tid >> 6;
  if (lane == 0) {
    #pragma unroll
    for (int e = 0; e < NE; ++e) wsred[wave][e] = d[e];
  }
  __syncthreads();

  if (tid == 0) {
    double best = -1e300; int bi = 0;
    #pragma unroll
    for (int e = 0; e < NE; ++e) {
      const double v = wsred[0][e] + wsred[1][e] + wsred[2][e] + wsred[3][e] + (double)bg[e];
      if (v > best) { best = v; bi = e; }
    }
    const int pos = atomicAdd(&counts[bi], 1);
    rowlist[bi * B_ROWS + pos] = b;
  }
}

__global__ __launch_bounds__(256) void gate_fallback(
    const float* __restrict__ t, const float* __restrict__ Wg,
    const float* __restrict__ bg, int* __restrict__ counts,
    int* __restrict__ rowlist)
{
  const int b   = blockIdx.x;
  const int tid = threadIdx.x;
  const float* tb = t + (size_t)b * T_DIM * OUT_DIM;

  float part[NE];
  #pragma unroll
  for (int e = 0; e < NE; ++e) part[e] = 0.f;
  #pragma unroll
  for (int it = 0; it < 4; ++it) {
    const int c = (tid + it * 256) * 4;
    float4 s = make_float4(0.f, 0.f, 0.f, 0.f);
    #pragma unroll
    for (int tt = 0; tt < T_DIM; ++tt) {
      const float4 v = *(const float4*)(tb + (size_t)tt * OUT_DIM + c);
      s.x += v.x; s.y += v.y; s.z += v.z; s.w += v.w;
    }
    const float mm[4] = { s.x * 0.125f, s.y * 0.125f, s.z * 0.125f, s.w * 0.125f };
    #pragma unroll
    for (int j = 0; j < 4; ++j) {
      const float* wg = Wg + (size_t)(c + j) * NE;
      #pragma unroll
      for (int e = 0; e < NE; ++e) part[e] += mm[j] * wg[e];
    }
  }
  double d[NE];
  #pragma unroll
  for (int e = 0; e < NE; ++e) d[e] = (double)part[e];
  #pragma unroll
  for (int off = 32; off > 0; off >>= 1) {
    #pragma unroll
    for (int e = 0; e < NE; ++e) d[e] += __shfl_down(d[e], off, 64);
  }
  __shared__ double wsred[4][NE];
  const int lane = tid & 63, wave = tid >> 6;
  if (lane == 0) {
    #pragma unroll
    for (int e = 0; e < NE; ++e) wsred[wave][e] = d[e];
  }
  __syncthreads();
  if (tid == 0) {
    double best = -1e300; int bi = 0;
    #pragma unroll
    for (int e = 0; e < NE; ++e) {
      const double v = wsred[0][e] + wsred[1][e] + wsred[2][e] + wsred[3][e] + (double)bg[e];
      if (v > best) { best = v; bi = e; }
    }
    const int pos = atomicAdd(&counts[bi], 1);
    rowlist[bi * B_ROWS + pos] = b;
  }
}

// ---------------- kernel X: pack gathered x into bf16 fragment-slot order --
__global__ __launch_bounds__(256) void pack_x(
    const float* __restrict__ x, const int* __restrict__ counts,
    const int* __restrict__ rowlist, short8* __restrict__ pxa)
{
  const int e   = blockIdx.x;
  const int rt  = blockIdx.y;
  const int it  = blockIdx.z;
  const int cnt = counts[e];
  const int row0 = rt * M_TILE;
  if (row0 >= cnt) return;
  const int* rl = rowlist + e * B_ROWS;
  const int tid = threadIdx.x;
  const int sg = (tid >> 4) & 3, slr = tid & 15, smb = tid >> 6;

  int g0 = row0 + smb * 16 + slr;        g0 = g0 < cnt ? g0 : cnt - 1;
  int g1 = row0 + (smb + 4) * 16 + slr;  g1 = g1 < cnt ? g1 : cnt - 1;
  const float* xp0 = x + (size_t)rl[g0] * IN_DIM + sg * 8 + it * K_STEP;
  const float* xp1 = x + (size_t)rl[g1] * IN_DIM + sg * 8 + it * K_STEP;

  const float4 a = *(const float4*)xp0, b = *(const float4*)(xp0 + 4);
  const float4 c = *(const float4*)xp1, d = *(const float4*)(xp1 + 4);
  S8U v0, v1;
  v0.u[0] = cvt2(a.x, a.y); v0.u[1] = cvt2(a.z, a.w);
  v0.u[2] = cvt2(b.x, b.y); v0.u[3] = cvt2(b.z, b.w);
  v1.u[0] = cvt2(c.x, c.y); v1.u[1] = cvt2(c.z, c.w);
  v1.u[2] = cvt2(d.x, d.y); v1.u[3] = cvt2(d.z, d.w);

  short8* dst = pxa + ((size_t)(e * PACK_TILES + rt) * NSTEP + it) * 512;
  dst[tid]       = v0.s;
  dst[tid + 256] = v1.s;
}

// ---------------- kernel B16w: 16-wave 256x256 GEMM ------------------------
// 192 blocks (12e x 16cb), 1024 threads: 16 waves/CU resident (4/SIMD,
// needs VGPR<=128 -> per-wave acc 4x4 like the proven r13 shape).
// Min delivered bytes (320 MB total, 1.67 MB/CU) + full latency hiding.
// Per wave per step: 1 A-DMA + 8 W scalar loads + 4 cvt + 1 ds_write +
// 8 ds_read + 16 MFMA; counted vmcnt(8) drains A(it), W(it+1) stays flying.
__global__ __launch_bounds__(1024) void expert_gemm16w(
    const float* __restrict__ W, const float* __restrict__ bias,
    const int* __restrict__ counts, const int* __restrict__ rowlist,
    const short8* __restrict__ pxa, float* __restrict__ out)
{
  const int bid = blockIdx.x;                   // [0,192)
  const int wk  = (bid & 7) * 24 + (bid >> 3);  // bijective; XCD k: [24k,24k+24)
  const int e   = wk >> 4;
  const int cb  = wk & 15;
  const int cnt = counts[e];
  const int c0  = cb * 256;
  const int* rl = rowlist + e * B_ROWS;

  __shared__ short8 xa[2][1024];   // 32 KiB: 256 rows x 32 k
  __shared__ short8 wb[2][1024];   // 32 KiB: 256 cols x 32 k

  const int tid  = threadIdx.x;    // 0..1023
  const int lane = tid & 63;
  const int wave = tid >> 6;       // 0..15

  // W staging: thread -> slot tid. slot s: col=(s>>6)*16+(s&15), k=((s>>4)&3)*8+j
  const int g = (tid >> 4) & 3, lc = tid & 15, nb = tid >> 6;
  const float* wp = W + (size_t)e * IN_DIM * OUT_DIM
                      + (size_t)(g * 8) * OUT_DIM + c0 + nb * 16 + lc;

  // A staging: wave w stages xa slots [w*64,(w+1)*64):
  // pxa slice = w>>3, slice-local offset (w&7)*64
  const short8* at = pxa + (size_t)(e * PACK_TILES + (wave >> 3)) * NSTEP * 512
                   + (wave & 7) * 64 + lane;

  // MFMA geometry: wave w -> rows [(w>>2)*64,+64) x cols [(w&3)*64,+64)
  const int wm = (wave >> 2) * 64;
  const int wn = (wave & 3) * 64;
  const int abase = (wave >> 2) * 256;
  const int bbase = (wave & 3) * 256;

  f32x4 acc[4][4];
  #pragma unroll
  for (int m = 0; m < 4; ++m)
    #pragma unroll
    for (int n = 0; n < 4; ++n)
      #pragma unroll
      for (int q = 0; q < 4; ++q) acc[m][n][q] = 0.f;

  float w0[8];

#define W_ISSUE(K)                                                      \
  {                                                                     \
    const float* p = wp + (size_t)(K) * OUT_DIM;                        \
    _Pragma("unroll")                                                   \
    for (int j = 0; j < 8; ++j) w0[j] = p[(size_t)j * OUT_DIM];         \
  }
#define A_DMA(IT, BUF)                                                  \
  {                                                                     \
    gload_lds16(at + (size_t)(IT) * 512, &xa[BUF][wave * 64]);          \
    __builtin_amdgcn_sched_barrier(0);                                  \
  }

  W_ISSUE(0);
  A_DMA(0, 0);

  for (int it = 0; it < NSTEP; ++it) {
    const int buf = it & 1;
    const int itn = (it + 1) & (NSTEP - 1);   // wrap keeps vmcnt uniform

    // convert W(it): dep-wait drains its 8 loads; A(it) DMA stays in flight
    S8U bv;
    #pragma unroll
    for (int q = 0; q < 4; ++q)
      bv.u[q] = cvt2(w0[2 * q], w0[2 * q + 1]);

    W_ISSUE(itn * K_STEP);        // 8 loads in flight across the barrier
    wb[buf][tid] = bv.s;

    // drain A(it) (1 oldest) + ds_write; keep W(it+1) (8 youngest) flying
    asm volatile("s_waitcnt vmcnt(8) lgkmcnt(0)" ::: "memory");
    __builtin_amdgcn_s_barrier();

    A_DMA(itn, buf ^ 1);          // safe: all reads of buf^1 completed

    short8 af[4], bf[4];
    #pragma unroll
    for (int m = 0; m < 4; ++m) af[m] = xa[buf][abase + m * 64 + lane];
    #pragma unroll
    for (int n = 0; n < 4; ++n) bf[n] = wb[buf][bbase + n * 64 + lane];
    #pragma unroll
    for (int m = 0; m < 4; ++m)
      #pragma unroll
      for (int n = 0; n < 4; ++n)
        acc[m][n] = __builtin_amdgcn_mfma_f32_16x16x32_bf16(af[m], bf[n], acc[m][n], 0, 0, 0);
  }
#undef W_ISSUE
#undef A_DMA

  // epilogue: C/D layout col = lane&15, row = (lane>>4)*4 + r
  const int lr = lane & 15;
  const int lq = (lane >> 4) * 4;
  float bcol[4];
  #pragma unroll
  for (int n = 0; n < 4; ++n)
    bcol[n] = bias[e * OUT_DIM + c0 + wn + n * 16 + lr];

  #pragma unroll
  for (int m = 0; m < 4; ++m) {
    #pragma unroll
    for (int r = 0; r < 4; ++r) {
      const int gidx = wm + m * 16 + lq + r;
      if (gidx >= cnt) continue;
      const int grow = rl[gidx];
      float* orow = out + (size_t)grow * OUT_DIM;
      #pragma unroll
      for (int n = 0; n < 4; ++n) {
        const int col = c0 + wn + n * 16 + lr;
        orow[col] = acc[m][n][r] + bcol[n];
      }
    }
  }
}

// ---------------- kernel B2: legacy r5 GEMM (fallback + cnt>256 catcher) ----
__global__ __launch_bounds__(256) void expert_gemm_legacy(
    const float* __restrict__ x, const float* __restrict__ W,
    const float* __restrict__ bias, const int* __restrict__ counts,
    const int* __restrict__ rowlist, float* __restrict__ out, int y_off)
{
  const int e    = blockIdx.z;
  const int cnt  = counts[e];
  const int row0 = (blockIdx.y + y_off) * M_TILE;
  if (row0 >= cnt) return;
  const int c0   = blockIdx.x * N_TILE;
  const int* rl  = rowlist + e * B_ROWS;

  __shared__ short8 xa[2][512];
  __shared__ short8 wb[2][512];

  const int tid  = threadIdx.x;
  const int lane = tid & 63;
  const int wave = tid >> 6;
  const int sg  = (tid >> 4) & 3;
  const int slr = tid & 15;
  const int smb = tid >> 6;

  int arow0, arow1;
  {
    const int g0 = row0 + smb * 16 + slr;
    const int g1 = row0 + (smb + 4) * 16 + slr;
    arow0 = rl[g0 < cnt ? g0 : cnt - 1];
    arow1 = rl[g1 < cnt ? g1 : cnt - 1];
  }
  const float* xp0 = x + (size_t)arow0 * IN_DIM + sg * 8;
  const float* xp1 = x + (size_t)arow1 * IN_DIM + sg * 8;
  const float* wp  = W + (size_t)e * IN_DIM * OUT_DIM
                       + (size_t)(sg * 8) * OUT_DIM + c0 + smb * 16 + slr;

  const int wm = (wave >> 1) * 64;
  const int wn = (wave & 1) * 64;
  const int abase = (wave >> 1) * 256;
  const int bbase = (wave & 1) * 256;

  f32x4 acc[4][4];
  #pragma unroll
  for (int m = 0; m < 4; ++m)
    #pragma unroll
    for (int n = 0; n < 4; ++n)
      #pragma unroll
      for (int q = 0; q < 4; ++q) acc[m][n][q] = 0.f;

  float4 a0lo, a0hi, a1lo, a1hi;
  float w0[8], w1[8];

#define ISSUE_LOADS(K)                                                  \
  {                                                                     \
    a0lo = *(const float4*)(xp0 + (K));                                 \
    a0hi = *(const float4*)(xp0 + (K) + 4);                             \
    a1lo = *(const float4*)(xp1 + (K));                                 \
    a1hi = *(const float4*)(xp1 + (K) + 4);                             \
    const float* p = wp + (size_t)(K) * OUT_DIM;                        \
    _Pragma("unroll")                                                   \
    for (int j = 0; j < 8; ++j) {                                       \
      w0[j] = p[(size_t)j * OUT_DIM];                                   \
      w1[j] = p[(size_t)j * OUT_DIM + 64];                              \
    }                                                                   \
  }

  ISSUE_LOADS(0);

  for (int it = 0; it < NSTEP; ++it) {
    S8U av0, av1, bv0, bv1;
    av0.u[0] = cvt2(a0lo.x, a0lo.y); av0.u[1] = cvt2(a0lo.z, a0lo.w);
    av0.u[2] = cvt2(a0hi.x, a0hi.y); av0.u[3] = cvt2(a0hi.z, a0hi.w);
    av1.u[0] = cvt2(a1lo.x, a1lo.y); av1.u[1] = cvt2(a1lo.z, a1lo.w);
    av1.u[2] = cvt2(a1hi.x, a1hi.y); av1.u[3] = cvt2(a1hi.z, a1hi.w);
    #pragma unroll
    for (int q = 0; q < 4; ++q) {
      bv0.u[q] = cvt2(w0[2 * q], w0[2 * q + 1]);
      bv1.u[q] = cvt2(w1[2 * q], w1[2 * q + 1]);
    }

    if (it + 1 < NSTEP) ISSUE_LOADS((it + 1) * K_STEP);

    const int buf = it & 1;
    xa[buf][tid]       = av0.s;
    xa[buf][tid + 256] = av1.s;
    wb[buf][tid]       = bv0.s;
    wb[buf][tid + 256] = bv1.s;
    barrier_lgkm();

    short8 af[4], bf[4];
    #pragma unroll
    for (int m = 0; m < 4; ++m) af[m] = xa[buf][abase + m * 64 + lane];
    #pragma unroll
    for (int n = 0; n < 4; ++n) bf[n] = wb[buf][bbase + n * 64 + lane];
    #pragma unroll
    for (int m = 0; m < 4; ++m)
      #pragma unroll
      for (int n = 0; n < 4; ++n)
        acc[m][n] = __builtin_amdgcn_mfma_f32_16x16x32_bf16(af[m], bf[n], acc[m][n], 0, 0, 0);
  }
#undef ISSUE_LOADS

  const int lr = lane & 15;
  const int lq = (lane >> 4) * 4;
  float bcol[4];
  #pragma unroll
  for (int n = 0; n < 4; ++n)
    bcol[n] = bias[e * OUT_DIM + c0 + wn + n * 16 + lr];

  #pragma unroll
  for (int m = 0; m < 4; ++m) {
    #pragma unroll
    for (int r = 0; r < 4; ++r) {
      const int gidx = row0 + wm + m * 16 + lq + r;
      if (gidx >= cnt) continue;
      const int grow = rl[gidx];
      float* orow = out + (size_t)grow * OUT_DIM;
      #pragma unroll
      for (int n = 0; n < 4; ++n) {
        const int col = c0 + wn + n * 16 + lr;
        orow[col] = acc[m][n][r] + bcol[n];
      }
    }
  }
}

extern "C" void kernel_launch(void* const* d_in, const int* in_sizes, int n_in,
                              void* d_out, int out_size, void* d_ws, size_t ws_size,
                              hipStream_t stream) {
  (void)in_sizes; (void)n_in; (void)out_size;
  const float* x  = (const float*)d_in[0];
  const float* t  = (const float*)d_in[1];
  const float* W  = (const float*)d_in[2];
  const float* bb = (const float*)d_in[3];
  const float* Wg = (const float*)d_in[4];
  const float* bg = (const float*)d_in[5];
  float* out = (float*)d_out;

  char*  base    = (char*)d_ws;
  int*   counts  = (int*)base;                       // 64 B
  int*   rowlist = (int*)(base + 64);                // 98304 B
  float* wgt     = (float*)(base + 98368);           // 196608 B -> ends 294976
  short8* pxa    = (short8*)(base + 295936);         // 6 MB
  const size_t need_wgt  = 294976;
  const size_t need_pack = 295936 + (size_t)NE * PACK_TILES * NSTEP * 512 * 16;

  hipMemsetAsync(counts, 0, 64, stream);
  if (ws_size >= need_wgt) {
    wg_transpose<<<OUT_DIM / 256, 256, 0, stream>>>(Wg, wgt);
    gate_kernel<<<B_ROWS, 256, 0, stream>>>(t, wgt, bg, counts, rowlist);
  } else {
    gate_fallback<<<B_ROWS, 256, 0, stream>>>(t, Wg, bg, counts, rowlist);
  }

  if (ws_size >= need_pack) {
    pack_x<<<dim3(NE, PACK_TILES, NSTEP), 256, 0, stream>>>(x, counts, rowlist, pxa);
    expert_gemm16w<<<dim3(NE * NCB16, 1, 1), 1024, 0, stream>>>(
        W, bb, counts, rowlist, pxa, out);
    // catcher for the (statistically impossible) cnt > 256 tail
    expert_gemm_legacy<<<dim3(NCB, B_ROWS / M_TILE - PACK_TILES, NE),
                         256, 0, stream>>>(x, W, bb, counts, rowlist, out, PACK_TILES);
  } else {
    expert_gemm_legacy<<<dim3(NCB, B_ROWS / M_TILE, NE),
                         256, 0, stream>>>(x, W, bb, counts, rowlist, out, 0);
  }
}

// Round 17
// 141.235 us; speedup vs baseline: 1.1682x; 1.0273x over previous
//
#include <hip/hip_runtime.h>
#include <hip/hip_bf16.h>

#define B_ROWS  2048
#define T_DIM   8
#define IN_DIM  1024
#define OUT_DIM 4096
#define NE      12

#define M_TILE 128
#define N_TILE 128
#define K_STEP 32
#define NSTEP  (IN_DIM / K_STEP)
#define PACK_TILES 2
#define NCB    (OUT_DIM / N_TILE)   // 32

typedef __attribute__((ext_vector_type(8))) short short8;
typedef __attribute__((ext_vector_type(4))) float f32x4;

union S8U { short8 s; unsigned u[4]; };

__device__ __forceinline__ unsigned cvt2(float a, float b) {
  __hip_bfloat162 h = __float22bfloat162_rn(make_float2(a, b));
  union { __hip_bfloat162 h; unsigned u; } c; c.h = h;
  return c.u;
}

__device__ __forceinline__ void barrier_lgkm() {
  asm volatile("s_waitcnt lgkmcnt(0)" ::: "memory");
  __builtin_amdgcn_s_barrier();
}

__device__ __forceinline__ void gload_lds16(const void* g, void* l) {
  __builtin_amdgcn_global_load_lds(
      (const __attribute__((address_space(1))) void*)g,
      (__attribute__((address_space(3))) void*)l, 16, 0, 0);
}

// ---------------- kernel P: transpose Wg[4096][12] -> WgT[12][4096] --------
__global__ __launch_bounds__(256) void wg_transpose(
    const float* __restrict__ Wg, float* __restrict__ wgt)
{
  const int c = blockIdx.x * 256 + threadIdx.x;
  #pragma unroll
  for (int e = 0; e < NE; ++e)
    wgt[(size_t)e * OUT_DIM + c] = Wg[(size_t)c * NE + e];
}

// ---------------- kernel A: gate (proven version, unchanged) ---------------
__global__ __launch_bounds__(256) void gate_kernel(
    const float* __restrict__ t, const float* __restrict__ wgt,
    const float* __restrict__ bg, int* __restrict__ counts,
    int* __restrict__ rowlist)
{
  const int b   = blockIdx.x;
  const int tid = threadIdx.x;
  const float* tb = t + (size_t)b * T_DIM * OUT_DIM;

  float4 m[4];
  #pragma unroll
  for (int it = 0; it < 4; ++it) {
    const int c = (tid + it * 256) * 4;
    float4 s = make_float4(0.f, 0.f, 0.f, 0.f);
    #pragma unroll
    for (int tt = 0; tt < T_DIM; ++tt) {
      const float4 v = *(const float4*)(tb + (size_t)tt * OUT_DIM + c);
      s.x += v.x; s.y += v.y; s.z += v.z; s.w += v.w;
    }
    m[it] = make_float4(s.x * 0.125f, s.y * 0.125f, s.z * 0.125f, s.w * 0.125f);
  }

  float part[NE];
  #pragma unroll
  for (int e = 0; e < NE; ++e) {
    float acc = 0.f;
    #pragma unroll
    for (int it = 0; it < 4; ++it) {
      const int c = (tid + it * 256) * 4;
      const float4 w = *(const float4*)(wgt + (size_t)e * OUT_DIM + c);
      acc += m[it].x * w.x; acc += m[it].y * w.y;
      acc += m[it].z * w.z; acc += m[it].w * w.w;
    }
    part[e] = acc;
  }

  double d[NE];
  #pragma unroll
  for (int e = 0; e < NE; ++e) d[e] = (double)part[e];
  #pragma unroll
  for (int off = 32; off > 0; off >>= 1) {
    #pragma unroll
    for (int e = 0; e < NE; ++e) d[e] += __shfl_down(d[e], off, 64);
  }

  __shared__ double wsred[4][NE];
  const int lane = tid & 63, wave = tid >> 6;
  if (lane == 0) {
    #pragma unroll
    for (int e = 0; e < NE; ++e) wsred[wave][e] = d[e];
  }
  __syncthreads();

  if (tid == 0) {
    double best = -1e300; int bi = 0;
    #pragma unroll
    for (int e = 0; e < NE; ++e) {
      const double v = wsred[0][e] + wsred[1][e] + wsred[2][e] + wsred[3][e] + (double)bg[e];
      if (v > best) { best = v; bi = e; }
    }
    const int pos = atomicAdd(&counts[bi], 1);
    rowlist[bi * B_ROWS + pos] = b;
  }
}

__global__ __launch_bounds__(256) void gate_fallback(
    const float* __restrict__ t, const float* __restrict__ Wg,
    const float* __restrict__ bg, int* __restrict__ counts,
    int* __restrict__ rowlist)
{
  const int b   = blockIdx.x;
  const int tid = threadIdx.x;
  const float* tb = t + (size_t)b * T_DIM * OUT_DIM;

  float part[NE];
  #pragma unroll
  for (int e = 0; e < NE; ++e) part[e] = 0.f;
  #pragma unroll
  for (int it = 0; it < 4; ++it) {
    const int c = (tid + it * 256) * 4;
    float4 s = make_float4(0.f, 0.f, 0.f, 0.f);
    #pragma unroll
    for (int tt = 0; tt < T_DIM; ++tt) {
      const float4 v = *(const float4*)(tb + (size_t)tt * OUT_DIM + c);
      s.x += v.x; s.y += v.y; s.z += v.z; s.w += v.w;
    }
    const float mm[4] = { s.x * 0.125f, s.y * 0.125f, s.z * 0.125f, s.w * 0.125f };
    #pragma unroll
    for (int j = 0; j < 4; ++j) {
      const float* wg = Wg + (size_t)(c + j) * NE;
      #pragma unroll
      for (int e = 0; e < NE; ++e) part[e] += mm[j] * wg[e];
    }
  }
  double d[NE];
  #pragma unroll
  for (int e = 0; e < NE; ++e) d[e] = (double)part[e];
  #pragma unroll
  for (int off = 32; off > 0; off >>= 1) {
    #pragma unroll
    for (int e = 0; e < NE; ++e) d[e] += __shfl_down(d[e], off, 64);
  }
  __shared__ double wsred[4][NE];
  const int lane = tid & 63, wave = tid >> 6;
  if (lane == 0) {
    #pragma unroll
    for (int e = 0; e < NE; ++e) wsred[wave][e] = d[e];
  }
  __syncthreads();
  if (tid == 0) {
    double best = -1e300; int bi = 0;
    #pragma unroll
    for (int e = 0; e < NE; ++e) {
      const double v = wsred[0][e] + wsred[1][e] + wsred[2][e] + wsred[3][e] + (double)bg[e];
      if (v > best) { best = v; bi = e; }
    }
    const int pos = atomicAdd(&counts[bi], 1);
    rowlist[bi * B_ROWS + pos] = b;
  }
}

// ---------------- kernel X: pack gathered x into bf16 fragment-slot order --
__global__ __launch_bounds__(256) void pack_x(
    const float* __restrict__ x, const int* __restrict__ counts,
    const int* __restrict__ rowlist, short8* __restrict__ pxa)
{
  const int e   = blockIdx.x;
  const int rt  = blockIdx.y;
  const int it  = blockIdx.z;
  const int cnt = counts[e];
  const int row0 = rt * M_TILE;
  if (row0 >= cnt) return;
  const int* rl = rowlist + e * B_ROWS;
  const int tid = threadIdx.x;
  const int sg = (tid >> 4) & 3, slr = tid & 15, smb = tid >> 6;

  int g0 = row0 + smb * 16 + slr;        g0 = g0 < cnt ? g0 : cnt - 1;
  int g1 = row0 + (smb + 4) * 16 + slr;  g1 = g1 < cnt ? g1 : cnt - 1;
  const float* xp0 = x + (size_t)rl[g0] * IN_DIM + sg * 8 + it * K_STEP;
  const float* xp1 = x + (size_t)rl[g1] * IN_DIM + sg * 8 + it * K_STEP;

  const float4 a = *(const float4*)xp0, b = *(const float4*)(xp0 + 4);
  const float4 c = *(const float4*)xp1, d = *(const float4*)(xp1 + 4);
  S8U v0, v1;
  v0.u[0] = cvt2(a.x, a.y); v0.u[1] = cvt2(a.z, a.w);
  v0.u[2] = cvt2(b.x, b.y); v0.u[3] = cvt2(b.z, b.w);
  v1.u[0] = cvt2(c.x, c.y); v1.u[1] = cvt2(c.z, c.w);
  v1.u[2] = cvt2(d.x, d.y); v1.u[3] = cvt2(d.z, d.w);

  short8* dst = pxa + ((size_t)(e * PACK_TILES + rt) * NSTEP + it) * 512;
  dst[tid]       = v0.s;
  dst[tid + 256] = v1.s;
}

// ---------------- kernel B8: r13 GEMM + dead-wave skip ----------------------
// Exact r13 structure (proven 140.8 us / ~88 us gemm, busy CUs saturated at
// the ~26 GB/s/CU delivery ceiling). New: cnt-aware wave gating. cnt~170 of
// the 256 staged rows are live; waves whose 32-row A-staging range or 64-row
// MFMA range lies wholly past cnt skip that work (barriers + W staging kept
// by ALL waves -- W slots feed other waves' B fragments). Cuts ~25% of pxa
// DMA bytes and ~25% of MFMAs at cnt~170, on the same saturated schedule.
__global__ __launch_bounds__(512) void expert_gemm8(
    const float* __restrict__ W, const float* __restrict__ bias,
    const int* __restrict__ counts, const int* __restrict__ rowlist,
    const short8* __restrict__ pxa, float* __restrict__ out)
{
  const int bid = blockIdx.x;                   // [0,384)
  const int wk  = (bid & 7) * 48 + (bid >> 3);  // bijective; XCD k: [48k,48k+48)
  const int e   = wk >> 5;                      // 32 col-blocks per expert
  const int cb  = wk & 31;
  const int cnt = counts[e];
  const int c0  = cb * N_TILE;
  const int* rl = rowlist + e * B_ROWS;

  __shared__ short8 xa[2][1024];   // 32 KiB: 256 rows x 32 k
  __shared__ short8 wb[2][512];    // 16 KiB: 128 cols x 32 k

  const int tid  = threadIdx.x;    // 0..511
  const int lane = tid & 63;
  const int wave = tid >> 6;       // 0..7

  // W staging: thread -> slot tid. col = (tid>>6)*16 + (tid&15), k = 8*sg+j
  const int sg = (tid >> 4) & 3, slr = tid & 15, smb = tid >> 6;
  const float* wp = W + (size_t)e * IN_DIM * OUT_DIM
                      + (size_t)(sg * 8) * OUT_DIM + c0 + smb * 16 + slr;

  // A staging: wave w stages xa slots [w*128,(w+1)*128) = rows [32w, 32w+32)
  // (pxa slice rt = w>>2, slice-local slots (w&3)*128)
  const short8* at = pxa + (size_t)(e * PACK_TILES + (wave >> 2)) * NSTEP * 512
                   + (wave & 3) * 128 + lane;
  const bool a_live = (32 * wave) < cnt;          // staging rows [32w,32w+32)

  // MFMA geometry: wave w -> rows [(w>>1)*64, +64) x cols [(w&1)*64, +64)
  const int wm = (wave >> 1) * 64;
  const int wn = (wave & 1) * 64;
  const int abase = (wave >> 2) * 512 + ((wave >> 1) & 1) * 256;
  const int bbase = (wave & 1) * 256;
  const bool m_live = wm < cnt;                   // MFMA rows [wm, wm+64)

  f32x4 acc[4][4];
  #pragma unroll
  for (int m = 0; m < 4; ++m)
    #pragma unroll
    for (int n = 0; n < 4; ++n)
      #pragma unroll
      for (int q = 0; q < 4; ++q) acc[m][n][q] = 0.f;

  float w0[8];

#define W_ISSUE(K)                                                      \
  {                                                                     \
    const float* p = wp + (size_t)(K) * OUT_DIM;                        \
    _Pragma("unroll")                                                   \
    for (int j = 0; j < 8; ++j) w0[j] = p[(size_t)j * OUT_DIM];         \
  }
#define A_DMA(IT, BUF)                                                  \
  if (a_live) {                                                         \
    gload_lds16(at + (size_t)(IT) * 512,      &xa[BUF][wave * 128]);    \
    gload_lds16(at + (size_t)(IT) * 512 + 64, &xa[BUF][wave * 128 + 64]); \
    __builtin_amdgcn_sched_barrier(0);                                  \
  }

  W_ISSUE(0);
  A_DMA(0, 0);

  for (int it = 0; it < NSTEP; ++it) {
    const int buf = it & 1;
    const int itn = (it + 1) & (NSTEP - 1);   // wrap keeps vmcnt uniform

    // convert W(it): dep-wait drains the 8 W loads; A(it) DMAs stay in flight
    S8U bv;
    #pragma unroll
    for (int q = 0; q < 4; ++q)
      bv.u[q] = cvt2(w0[2 * q], w0[2 * q + 1]);

    W_ISSUE(itn * K_STEP);        // 8 loads in flight across the barrier
    wb[buf][tid] = bv.s;

    // drain A(it) (2 oldest) + ds_write; keep W(it+1) (8 youngest) in flight
    // (dead-A waves: only 8 W outstanding -> vmcnt(8) is a no-op, still safe)
    asm volatile("s_waitcnt vmcnt(8) lgkmcnt(0)" ::: "memory");
    __builtin_amdgcn_s_barrier();

    A_DMA(itn, buf ^ 1);          // safe: all reads of buf^1 completed

    if (m_live) {
      short8 af[4], bf[4];
      #pragma unroll
      for (int m = 0; m < 4; ++m) af[m] = xa[buf][abase + m * 64 + lane];
      #pragma unroll
      for (int n = 0; n < 4; ++n) bf[n] = wb[buf][bbase + n * 64 + lane];
      #pragma unroll
      for (int m = 0; m < 4; ++m)
        #pragma unroll
        for (int n = 0; n < 4; ++n)
          acc[m][n] = __builtin_amdgcn_mfma_f32_16x16x32_bf16(af[m], bf[n], acc[m][n], 0, 0, 0);
    }
  }
#undef W_ISSUE
#undef A_DMA

  // epilogue: C/D layout col = lane&15, row = (lane>>4)*4 + r
  if (!m_live) return;
  const int lr = lane & 15;
  const int lq = (lane >> 4) * 4;
  float bcol[4];
  #pragma unroll
  for (int n = 0; n < 4; ++n)
    bcol[n] = bias[e * OUT_DIM + c0 + wn + n * 16 + lr];

  #pragma unroll
  for (int m = 0; m < 4; ++m) {
    #pragma unroll
    for (int r = 0; r < 4; ++r) {
      const int gidx = wm + m * 16 + lq + r;
      if (gidx >= cnt) continue;
      const int grow = rl[gidx];
      float* orow = out + (size_t)grow * OUT_DIM;
      #pragma unroll
      for (int n = 0; n < 4; ++n) {
        const int col = c0 + wn + n * 16 + lr;
        orow[col] = acc[m][n][r] + bcol[n];
      }
    }
  }
}

// ---------------- kernel B2: legacy r5 GEMM (fallback + cnt>256 catcher) ----
__global__ __launch_bounds__(256) void expert_gemm_legacy(
    const float* __restrict__ x, const float* __restrict__ W,
    const float* __restrict__ bias, const int* __restrict__ counts,
    const int* __restrict__ rowlist, float* __restrict__ out, int y_off)
{
  const int e    = blockIdx.z;
  const int cnt  = counts[e];
  const int row0 = (blockIdx.y + y_off) * M_TILE;
  if (row0 >= cnt) return;
  const int c0   = blockIdx.x * N_TILE;
  const int* rl  = rowlist + e * B_ROWS;

  __shared__ short8 xa[2][512];
  __shared__ short8 wb[2][512];

  const int tid  = threadIdx.x;
  const int lane = tid & 63;
  const int wave = tid >> 6;
  const int sg  = (tid >> 4) & 3;
  const int slr = tid & 15;
  const int smb = tid >> 6;

  int arow0, arow1;
  {
    const int g0 = row0 + smb * 16 + slr;
    const int g1 = row0 + (smb + 4) * 16 + slr;
    arow0 = rl[g0 < cnt ? g0 : cnt - 1];
    arow1 = rl[g1 < cnt ? g1 : cnt - 1];
  }
  const float* xp0 = x + (size_t)arow0 * IN_DIM + sg * 8;
  const float* xp1 = x + (size_t)arow1 * IN_DIM + sg * 8;
  const float* wp  = W + (size_t)e * IN_DIM * OUT_DIM
                       + (size_t)(sg * 8) * OUT_DIM + c0 + smb * 16 + slr;

  const int wm = (wave >> 1) * 64;
  const int wn = (wave & 1) * 64;
  const int abase = (wave >> 1) * 256;
  const int bbase = (wave & 1) * 256;

  f32x4 acc[4][4];
  #pragma unroll
  for (int m = 0; m < 4; ++m)
    #pragma unroll
    for (int n = 0; n < 4; ++n)
      #pragma unroll
      for (int q = 0; q < 4; ++q) acc[m][n][q] = 0.f;

  float4 a0lo, a0hi, a1lo, a1hi;
  float w0[8], w1[8];

#define ISSUE_LOADS(K)                                                  \
  {                                                                     \
    a0lo = *(const float4*)(xp0 + (K));                                 \
    a0hi = *(const float4*)(xp0 + (K) + 4);                             \
    a1lo = *(const float4*)(xp1 + (K));                                 \
    a1hi = *(const float4*)(xp1 + (K) + 4);                             \
    const float* p = wp + (size_t)(K) * OUT_DIM;                        \
    _Pragma("unroll")                                                   \
    for (int j = 0; j < 8; ++j) {                                       \
      w0[j] = p[(size_t)j * OUT_DIM];                                   \
      w1[j] = p[(size_t)j * OUT_DIM + 64];                              \
    }                                                                   \
  }

  ISSUE_LOADS(0);

  for (int it = 0; it < NSTEP; ++it) {
    S8U av0, av1, bv0, bv1;
    av0.u[0] = cvt2(a0lo.x, a0lo.y); av0.u[1] = cvt2(a0lo.z, a0lo.w);
    av0.u[2] = cvt2(a0hi.x, a0hi.y); av0.u[3] = cvt2(a0hi.z, a0hi.w);
    av1.u[0] = cvt2(a1lo.x, a1lo.y); av1.u[1] = cvt2(a1lo.z, a1lo.w);
    av1.u[2] = cvt2(a1hi.x, a1hi.y); av1.u[3] = cvt2(a1hi.z, a1hi.w);
    #pragma unroll
    for (int q = 0; q < 4; ++q) {
      bv0.u[q] = cvt2(w0[2 * q], w0[2 * q + 1]);
      bv1.u[q] = cvt2(w1[2 * q], w1[2 * q + 1]);
    }

    if (it + 1 < NSTEP) ISSUE_LOADS((it + 1) * K_STEP);

    const int buf = it & 1;
    xa[buf][tid]       = av0.s;
    xa[buf][tid + 256] = av1.s;
    wb[buf][tid]       = bv0.s;
    wb[buf][tid + 256] = bv1.s;
    barrier_lgkm();

    short8 af[4], bf[4];
    #pragma unroll
    for (int m = 0; m < 4; ++m) af[m] = xa[buf][abase + m * 64 + lane];
    #pragma unroll
    for (int n = 0; n < 4; ++n) bf[n] = wb[buf][bbase + n * 64 + lane];
    #pragma unroll
    for (int m = 0; m < 4; ++m)
      #pragma unroll
      for (int n = 0; n < 4; ++n)
        acc[m][n] = __builtin_amdgcn_mfma_f32_16x16x32_bf16(af[m], bf[n], acc[m][n], 0, 0, 0);
  }
#undef ISSUE_LOADS

  const int lr = lane & 15;
  const int lq = (lane >> 4) * 4;
  float bcol[4];
  #pragma unroll
  for (int n = 0; n < 4; ++n)
    bcol[n] = bias[e * OUT_DIM + c0 + wn + n * 16 + lr];

  #pragma unroll
  for (int m = 0; m < 4; ++m) {
    #pragma unroll
    for (int r = 0; r < 4; ++r) {
      const int gidx = row0 + wm + m * 16 + lq + r;
      if (gidx >= cnt) continue;
      const int grow = rl[gidx];
      float* orow = out + (size_t)grow * OUT_DIM;
      #pragma unroll
      for (int n = 0; n < 4; ++n) {
        const int col = c0 + wn + n * 16 + lr;
        orow[col] = acc[m][n][r] + bcol[n];
      }
    }
  }
}

extern "C" void kernel_launch(void* const* d_in, const int* in_sizes, int n_in,
                              void* d_out, int out_size, void* d_ws, size_t ws_size,
                              hipStream_t stream) {
  (void)in_sizes; (void)n_in; (void)out_size;
  const float* x  = (const float*)d_in[0];
  const float* t  = (const float*)d_in[1];
  const float* W  = (const float*)d_in[2];
  const float* bb = (const float*)d_in[3];
  const float* Wg = (const float*)d_in[4];
  const float* bg = (const float*)d_in[5];
  float* out = (float*)d_out;

  char*  base    = (char*)d_ws;
  int*   counts  = (int*)base;                       // 64 B
  int*   rowlist = (int*)(base + 64);                // 98304 B
  float* wgt     = (float*)(base + 98368);           // 196608 B -> ends 294976
  short8* pxa    = (short8*)(base + 295936);         // 6 MB
  const size_t need_wgt  = 294976;
  const size_t need_pack = 295936 + (size_t)NE * PACK_TILES * NSTEP * 512 * 16;

  hipMemsetAsync(counts, 0, 64, stream);
  if (ws_size >= need_wgt) {
    wg_transpose<<<OUT_DIM / 256, 256, 0, stream>>>(Wg, wgt);
    gate_kernel<<<B_ROWS, 256, 0, stream>>>(t, wgt, bg, counts, rowlist);
  } else {
    gate_fallback<<<B_ROWS, 256, 0, stream>>>(t, Wg, bg, counts, rowlist);
  }

  if (ws_size >= need_pack) {
    pack_x<<<dim3(NE, PACK_TILES, NSTEP), 256, 0, stream>>>(x, counts, rowlist, pxa);
    expert_gemm8<<<dim3(NE * NCB, 1, 1), 512, 0, stream>>>(
        W, bb, counts, rowlist, pxa, out);
    // catcher for the (statistically impossible) cnt > 256 tail
    expert_gemm_legacy<<<dim3(NCB, B_ROWS / M_TILE - PACK_TILES, NE),
                         256, 0, stream>>>(x, W, bb, counts, rowlist, out, PACK_TILES);
  } else {
    expert_gemm_legacy<<<dim3(NCB, B_ROWS / M_TILE, NE),
                         256, 0, stream>>>(x, W, bb, counts, rowlist, out, 0);
  }
}